// Round 1
// baseline (9917.435 us; speedup 1.0000x reference)
//
#include <hip/hip_runtime.h>
#include <math.h>

#define NN 50000
#define EE 800000
#define DD 256
#define HH 8
#define CC 32
#define EDIMK 16
#define LL 6
#define HID 1024
#define NEG 0.2f
#define LNEPS 1e-5f

static __device__ __forceinline__ float4 ld4(const float* p) {
    return *reinterpret_cast<const float4*>(p);
}
static __device__ __forceinline__ void st4(float* p, float4 v) {
    *reinterpret_cast<float4*>(p) = v;
}

// ---- precompute: w_eh[k][h] = sum_c W_edge[k, h*32+c] * att_edge[h, c] ----
__global__ void k_weh(const float* __restrict__ W_edge, const float* __restrict__ att_edge,
                      float* __restrict__ w_eh) {
    int t = threadIdx.x;
    if (t < EDIMK * HH) {
        int k = t >> 3, h = t & 7;
        float s = 0.f;
        for (int c = 0; c < CC; ++c) s += W_edge[k * DD + h * CC + c] * att_edge[h * CC + c];
        w_eh[t] = s;
    }
}

// ---- per-edge a_edge + deg + self-loop accumulation (linearity of mean) ----
__global__ void k_edge_pre(const float* __restrict__ edge_attr, const int* __restrict__ ei,
                           const float* __restrict__ w_eh, float* __restrict__ a_edge,
                           int* __restrict__ deg) {
    __shared__ float sw[EDIMK * HH];
    if (threadIdx.x < EDIMK * HH) sw[threadIdx.x] = w_eh[threadIdx.x];
    __syncthreads();
    int e = blockIdx.x * blockDim.x + threadIdx.x;
    if (e >= EE) return;
    float ea[EDIMK];
#pragma unroll
    for (int k4 = 0; k4 < EDIMK; k4 += 4) {
        float4 v = ld4(edge_attr + (size_t)e * EDIMK + k4);
        ea[k4] = v.x; ea[k4 + 1] = v.y; ea[k4 + 2] = v.z; ea[k4 + 3] = v.w;
    }
    float ah[HH];
#pragma unroll
    for (int h = 0; h < HH; ++h) {
        float s = 0.f;
#pragma unroll
        for (int k = 0; k < EDIMK; ++k) s += ea[k] * sw[k * HH + h];
        ah[h] = s;
    }
#pragma unroll
    for (int h = 0; h < HH; ++h) a_edge[(size_t)e * HH + h] = ah[h];
    int dst = ei[EE + e];
    atomicAdd(&deg[dst], 1);
    float* selfp = a_edge + ((size_t)EE + dst) * HH;
#pragma unroll
    for (int h = 0; h < HH; ++h) atomicAdd(&selfp[h], ah[h]);
}

__global__ void k_self_fin(float* __restrict__ a_edge, const int* __restrict__ deg) {
    int t = blockIdx.x * blockDim.x + threadIdx.x;
    if (t >= NN * HH) return;
    int n = t >> 3;
    int d = deg[n]; if (d < 1) d = 1;
    a_edge[((size_t)EE + n) * HH + (t & 7)] /= (float)d;
}

// ---- one-block exclusive scan of deg -> rowptr ----
__global__ void k_scan(const int* __restrict__ deg, int* __restrict__ rowptr) {
    __shared__ int sd[1024];
    __shared__ int soff;
    int tid = threadIdx.x;
    if (tid == 0) { soff = 0; rowptr[0] = 0; }
    __syncthreads();
    for (int base = 0; base < NN; base += 1024) {
        int v = (base + tid < NN) ? deg[base + tid] : 0;
        sd[tid] = v;
        __syncthreads();
        for (int s = 1; s < 1024; s <<= 1) {
            int t2 = (tid >= s) ? sd[tid - s] : 0;
            __syncthreads();
            sd[tid] += t2;
            __syncthreads();
        }
        int incl = sd[tid];
        int off = soff;
        if (base + tid < NN) rowptr[base + tid + 1] = off + incl;
        __syncthreads();
        if (tid == 1023) soff = off + incl;
        __syncthreads();
    }
}

__global__ void k_scatter(const int* __restrict__ ei, const int* __restrict__ rowptr,
                          int* __restrict__ cursor, int* __restrict__ s_src,
                          int* __restrict__ s_eid) {
    int e = blockIdx.x * blockDim.x + threadIdx.x;
    if (e >= EE) return;
    int dst = ei[EE + e];
    int p = rowptr[dst] + atomicAdd(&cursor[dst], 1);
    s_src[p] = ei[e];
    s_eid[p] = e;
}

// ---- generic fp32 tiled GEMM: C[M,Nc] = A[M,K] @ B[K,Nc] (+bias, relu) ----
__global__ __launch_bounds__(256) void k_gemm(const float* __restrict__ A,
                                              const float* __restrict__ B,
                                              const float* __restrict__ bias,
                                              float* __restrict__ C,
                                              int M, int Nc, int K, int relu) {
    __shared__ float As[16][68];
    __shared__ float Bs[16][68];
    int tid = threadIdx.x;
    int tx = tid & 15, ty = tid >> 4;
    int rowBase = blockIdx.y * 64, colBase = blockIdx.x * 64;
    float acc[4][4] = {};
    int ar = tid >> 2;
    int ak = (tid & 3) * 4;
    int bk = tid >> 4;
    int bc = (tid & 15) * 4;
    for (int k0 = 0; k0 < K; k0 += 16) {
        float4 av = make_float4(0.f, 0.f, 0.f, 0.f);
        if (rowBase + ar < M) av = ld4(A + (size_t)(rowBase + ar) * K + k0 + ak);
        float4 bv = ld4(B + (size_t)(k0 + bk) * Nc + colBase + bc);
        __syncthreads();
        As[ak + 0][ar] = av.x; As[ak + 1][ar] = av.y;
        As[ak + 2][ar] = av.z; As[ak + 3][ar] = av.w;
        st4(&Bs[bk][bc], bv);
        __syncthreads();
#pragma unroll
        for (int kk = 0; kk < 16; ++kk) {
            float4 a4 = *reinterpret_cast<float4*>(&As[kk][ty * 4]);
            float4 b4 = *reinterpret_cast<float4*>(&Bs[kk][tx * 4]);
            acc[0][0] += a4.x * b4.x; acc[0][1] += a4.x * b4.y; acc[0][2] += a4.x * b4.z; acc[0][3] += a4.x * b4.w;
            acc[1][0] += a4.y * b4.x; acc[1][1] += a4.y * b4.y; acc[1][2] += a4.y * b4.z; acc[1][3] += a4.y * b4.w;
            acc[2][0] += a4.z * b4.x; acc[2][1] += a4.z * b4.y; acc[2][2] += a4.z * b4.z; acc[2][3] += a4.z * b4.w;
            acc[3][0] += a4.w * b4.x; acc[3][1] += a4.w * b4.y; acc[3][2] += a4.w * b4.z; acc[3][3] += a4.w * b4.w;
        }
    }
    int row0 = rowBase + ty * 4, col0 = colBase + tx * 4;
    float4 bv = make_float4(0.f, 0.f, 0.f, 0.f);
    if (bias) bv = ld4(bias + col0);
#pragma unroll
    for (int i = 0; i < 4; ++i) {
        if (row0 + i < M) {
            float4 o;
            o.x = acc[i][0] + bv.x; o.y = acc[i][1] + bv.y;
            o.z = acc[i][2] + bv.z; o.w = acc[i][3] + bv.w;
            if (relu) {
                o.x = o.x > 0.f ? o.x : 0.f; o.y = o.y > 0.f ? o.y : 0.f;
                o.z = o.z > 0.f ? o.z : 0.f; o.w = o.w > 0.f ? o.w : 0.f;
            }
            st4(C + (size_t)(row0 + i) * Nc + col0, o);
        }
    }
}

// ---- a_src/a_dst: per (node, head) dot with attention vectors ----
__global__ void k_srcdst(const float* __restrict__ x_proj, const float* __restrict__ att_src,
                         const float* __restrict__ att_dst, float* __restrict__ a_src,
                         float* __restrict__ a_dst) {
    __shared__ float ss[DD], sd[DD];
    int tid = threadIdx.x;
    if (tid < DD) { ss[tid] = att_src[tid]; sd[tid] = att_dst[tid]; }
    __syncthreads();
    int t = blockIdx.x * blockDim.x + tid;
    if (t >= NN * HH) return;
    int n = t >> 3, h = t & 7;
    const float* xp = x_proj + (size_t)n * DD + h * CC;
    float s1 = 0.f, s2 = 0.f;
#pragma unroll
    for (int c = 0; c < CC; c += 4) {
        float4 v = ld4(xp + c);
        int b = h * CC + c;
        s1 += v.x * ss[b] + v.y * ss[b + 1] + v.z * ss[b + 2] + v.w * ss[b + 3];
        s2 += v.x * sd[b] + v.y * sd[b + 1] + v.z * sd[b + 2] + v.w * sd[b + 3];
    }
    a_src[t] = s1;
    a_dst[t] = s2;
}

// ---- edge softmax numerators + denominator accumulation ----
__global__ void k_edge_soft(const int* __restrict__ ei, const float* __restrict__ a_src,
                            const float* __restrict__ a_dst, const float* __restrict__ a_edge,
                            float* __restrict__ ex, float* __restrict__ denom) {
    int e = blockIdx.x * blockDim.x + threadIdx.x;
    if (e >= EE + NN) return;
    int src, dst;
    if (e < EE) { src = ei[e]; dst = ei[EE + e]; }
    else { src = e - EE; dst = src; }
    const float* as = a_src + (size_t)src * HH;
    const float* ad = a_dst + (size_t)dst * HH;
    const float* ae = a_edge + (size_t)e * HH;
    float* exp_ = ex + (size_t)e * HH;
#pragma unroll
    for (int h = 0; h < HH; ++h) {
        float al = as[h] + ad[h] + ae[h];
        al = al > 0.f ? al : NEG * al;
        float v = expf(al);
        exp_[h] = v;
        atomicAdd(&denom[(size_t)dst * HH + h], v);
    }
}

// ---- CSR gather aggregation: one wave per node, 4 channels per lane ----
__global__ __launch_bounds__(256) void k_agg(const float* __restrict__ x_proj,
                                             const float* __restrict__ ex,
                                             const float* __restrict__ denom,
                                             const int* __restrict__ rowptr,
                                             const int* __restrict__ s_src,
                                             const int* __restrict__ s_eid,
                                             const float* __restrict__ bias,
                                             float* __restrict__ g) {
    int wid = (blockIdx.x * blockDim.x + threadIdx.x) >> 6;
    int lane = threadIdx.x & 63;
    if (wid >= NN) return;
    int n = wid;
    int c4 = lane * 4;
    int h = lane >> 3;
    float inv = 1.0f / denom[(size_t)n * HH + h];
    float wself = ex[((size_t)EE + n) * HH + h] * inv;
    float4 xp = ld4(x_proj + (size_t)n * DD + c4);
    float4 acc;
    acc.x = xp.x * wself; acc.y = xp.y * wself; acc.z = xp.z * wself; acc.w = xp.w * wself;
    int k0 = rowptr[n], k1 = rowptr[n + 1];
    for (int k = k0; k < k1; ++k) {
        int s = s_src[k];
        int eid = s_eid[k];
        float w = ex[(size_t)eid * HH + h] * inv;
        float4 v = ld4(x_proj + (size_t)s * DD + c4);
        acc.x += v.x * w; acc.y += v.y * w; acc.z += v.z * w; acc.w += v.w * w;
    }
    float4 b = ld4(bias + c4);
    acc.x += b.x; acc.y += b.y; acc.z += b.z; acc.w += b.w;
    st4(g + (size_t)n * DD + c4, acc);
}

// ---- out = LayerNorm(a + b) * gamma + beta : one wave per row ----
__global__ __launch_bounds__(256) void k_addln(const float* __restrict__ a,
                                               const float* __restrict__ b,
                                               const float* __restrict__ gma,
                                               const float* __restrict__ bta,
                                               float* __restrict__ out) {
    int wid = (blockIdx.x * blockDim.x + threadIdx.x) >> 6;
    int lane = threadIdx.x & 63;
    if (wid >= NN) return;
    size_t base = (size_t)wid * DD + lane * 4;
    float4 va = ld4(a + base), vb = ld4(b + base);
    float4 v;
    v.x = va.x + vb.x; v.y = va.y + vb.y; v.z = va.z + vb.z; v.w = va.w + vb.w;
    float s = v.x + v.y + v.z + v.w;
    for (int off = 32; off; off >>= 1) s += __shfl_xor(s, off, 64);
    float mu = s * (1.0f / DD);
    float4 d;
    d.x = v.x - mu; d.y = v.y - mu; d.z = v.z - mu; d.w = v.w - mu;
    float q = d.x * d.x + d.y * d.y + d.z * d.z + d.w * d.w;
    for (int off = 32; off; off >>= 1) q += __shfl_xor(q, off, 64);
    float rs = rsqrtf(q * (1.0f / DD) + LNEPS);
    float4 g4 = ld4(gma + lane * 4), b4 = ld4(bta + lane * 4);
    float4 o;
    o.x = d.x * rs * g4.x + b4.x; o.y = d.y * rs * g4.y + b4.y;
    o.z = d.z * rs * g4.z + b4.z; o.w = d.w * rs * g4.w + b4.w;
    st4(out + base, o);
}

extern "C" void kernel_launch(void* const* d_in, const int* in_sizes, int n_in,
                              void* d_out, int out_size, void* d_ws, size_t ws_size,
                              hipStream_t stream) {
    const float* x        = (const float*)d_in[0];
    const int*   ei       = (const int*)d_in[1];
    const float* edge_attr= (const float*)d_in[2];
    const float* W        = (const float*)d_in[3];
    const float* att_src  = (const float*)d_in[4];
    const float* att_dst  = (const float*)d_in[5];
    const float* att_edge = (const float*)d_in[6];
    const float* W_edge   = (const float*)d_in[7];
    const float* bias     = (const float*)d_in[8];
    const float* ffn_w1   = (const float*)d_in[9];
    const float* ffn_b1   = (const float*)d_in[10];
    const float* ffn_w2   = (const float*)d_in[11];
    const float* ffn_b2   = (const float*)d_in[12];
    const float* ln1_g    = (const float*)d_in[13];
    const float* ln1_b    = (const float*)d_in[14];
    const float* ln2_g    = (const float*)d_in[15];
    const float* ln2_b    = (const float*)d_in[16];
    float* m = (float*)d_out;

    char* wp = (char*)d_ws;
    auto alloc = [&](size_t bytes) -> char* {
        char* p = wp;
        wp += (bytes + 255) & ~(size_t)255;
        return p;
    };
    float* a_edge = (float*)alloc((size_t)(EE + NN) * HH * 4);
    float* ex     = (float*)alloc((size_t)(EE + NN) * HH * 4);
    float* a_src  = (float*)alloc((size_t)NN * HH * 4);
    float* a_dst  = (float*)alloc((size_t)NN * HH * 4);
    float* denom  = (float*)alloc((size_t)NN * HH * 4);
    int*   deg    = (int*)alloc((size_t)NN * 4);
    int*   rowptr = (int*)alloc((size_t)(NN + 1) * 4);
    int*   cursor = (int*)alloc((size_t)NN * 4);
    int*   s_src  = (int*)alloc((size_t)EE * 4);
    int*   s_eid  = (int*)alloc((size_t)EE * 4);
    float* w_eh   = (float*)alloc((size_t)EDIMK * HH * 4);
    float* x_proj = (float*)alloc((size_t)NN * DD * 4);
    float* gbuf   = (float*)alloc((size_t)NN * DD * 4);
    size_t used = (size_t)(wp - (char*)d_ws);
    size_t avail = ws_size > used ? ws_size - used : 0;
    size_t maxrows = avail / ((size_t)HID * 4);
    int chunk = (int)(maxrows < (size_t)NN ? maxrows : (size_t)NN);
    if (chunk < 1) chunk = 1;
    float* h1 = (float*)wp;

    // m <- x
    hipMemcpyAsync(m, x, (size_t)NN * DD * 4, hipMemcpyDeviceToDevice, stream);
    hipMemsetAsync(deg, 0, (size_t)NN * 4, stream);
    hipMemsetAsync(cursor, 0, (size_t)NN * 4, stream);
    hipMemsetAsync(a_edge + (size_t)EE * HH, 0, (size_t)NN * HH * 4, stream);

    // layer-invariant precompute
    k_weh<<<1, 128, 0, stream>>>(W_edge, att_edge, w_eh);
    k_edge_pre<<<(EE + 255) / 256, 256, 0, stream>>>(edge_attr, ei, w_eh, a_edge, deg);
    k_self_fin<<<(NN * HH + 255) / 256, 256, 0, stream>>>(a_edge, deg);
    k_scan<<<1, 1024, 0, stream>>>(deg, rowptr);
    k_scatter<<<(EE + 255) / 256, 256, 0, stream>>>(ei, rowptr, cursor, s_src, s_eid);

    for (int i = 0; i < LL; ++i) {
        // x_proj = m @ W
        dim3 g1(DD / 64, (NN + 63) / 64);
        k_gemm<<<g1, 256, 0, stream>>>(m, W, nullptr, x_proj, NN, DD, DD, 0);
        k_srcdst<<<(NN * HH + 255) / 256, 256, 0, stream>>>(x_proj, att_src, att_dst, a_src, a_dst);
        hipMemsetAsync(denom, 0, (size_t)NN * HH * 4, stream);
        k_edge_soft<<<(EE + NN + 255) / 256, 256, 0, stream>>>(ei, a_src, a_dst, a_edge, ex, denom);
        k_agg<<<(NN * 64 + 255) / 256, 256, 0, stream>>>(x_proj, ex, denom, rowptr, s_src, s_eid, bias, gbuf);
        k_addln<<<(NN * 64 + 255) / 256, 256, 0, stream>>>(gbuf, m, ln1_g + i * DD, ln1_b + i * DD, m);
        // FFN (chunked over rows to fit workspace)
        for (int r0 = 0; r0 < NN; r0 += chunk) {
            int rows = (NN - r0) < chunk ? (NN - r0) : chunk;
            dim3 g2(HID / 64, (rows + 63) / 64);
            k_gemm<<<g2, 256, 0, stream>>>(m + (size_t)r0 * DD, ffn_w1 + (size_t)i * DD * HID,
                                           ffn_b1 + (size_t)i * HID, h1, rows, HID, DD, 1);
            dim3 g3(DD / 64, (rows + 63) / 64);
            k_gemm<<<g3, 256, 0, stream>>>(h1, ffn_w2 + (size_t)i * HID * DD,
                                           ffn_b2 + (size_t)i * DD, gbuf + (size_t)r0 * DD,
                                           rows, DD, HID, 0);
        }
        k_addln<<<(NN * 64 + 255) / 256, 256, 0, stream>>>(gbuf, m, ln2_g + i * DD, ln2_b + i * DD, m);
    }
}

// Round 2
// 2285.631 us; speedup vs baseline: 4.3390x; 4.3390x over previous
//
#include <hip/hip_runtime.h>
#include <math.h>

#define NN 50000
#define MP 50048           // NN padded to multiple of 128
#define EE 800000
#define DD 256
#define HH 8
#define CC 32
#define EDIMK 16
#define LL 6
#define HID 1024
#define NEG 0.2f
#define LNEPS 1e-5f

using short8  = __attribute__((ext_vector_type(8))) short;
using floatx4 = __attribute__((ext_vector_type(4))) float;

static __device__ __forceinline__ float4 ld4(const float* p) {
    return *reinterpret_cast<const float4*>(p);
}
static __device__ __forceinline__ void st4(float* p, float4 v) {
    *reinterpret_cast<float4*>(p) = v;
}
static __device__ __forceinline__ float b2f(unsigned short u) {
    union { unsigned int i; float f; } v; v.i = ((unsigned int)u) << 16; return v.f;
}
static __device__ __forceinline__ unsigned short f2b(float f) {
    union { float f; unsigned int i; } v; v.f = f;
    unsigned int r = (v.i + 0x7fffu + ((v.i >> 16) & 1u)) >> 16;
    return (unsigned short)r;
}
static __device__ __forceinline__ void gload_lds16(const ushort* g, ushort* l) {
    __builtin_amdgcn_global_load_lds((const __attribute__((address_space(1))) void*)g,
                                     (__attribute__((address_space(3))) void*)l, 16, 0, 0);
}

// ---- w_eh[k][h] = sum_c W_edge[k, h*32+c] * att_edge[h, c] ----
__global__ void k_weh(const float* __restrict__ W_edge, const float* __restrict__ att_edge,
                      float* __restrict__ w_eh) {
    int t = threadIdx.x;
    if (t < EDIMK * HH) {
        int k = t >> 3, h = t & 7;
        float s = 0.f;
        for (int c = 0; c < CC; ++c) s += W_edge[k * DD + h * CC + c] * att_edge[h * CC + c];
        w_eh[t] = s;
    }
}

// ---- per-edge a_edge + deg (no float atomics) ----
__global__ void k_edge_pre(const float* __restrict__ edge_attr, const int* __restrict__ ei,
                           const float* __restrict__ w_eh, float* __restrict__ a_edge,
                           int* __restrict__ deg) {
    __shared__ float sw[EDIMK * HH];
    if (threadIdx.x < EDIMK * HH) sw[threadIdx.x] = w_eh[threadIdx.x];
    __syncthreads();
    int e = blockIdx.x * blockDim.x + threadIdx.x;
    if (e >= EE) return;
    float ea[EDIMK];
#pragma unroll
    for (int k4 = 0; k4 < EDIMK; k4 += 4) {
        float4 v = ld4(edge_attr + (size_t)e * EDIMK + k4);
        ea[k4] = v.x; ea[k4 + 1] = v.y; ea[k4 + 2] = v.z; ea[k4 + 3] = v.w;
    }
#pragma unroll
    for (int h = 0; h < HH; ++h) {
        float s = 0.f;
#pragma unroll
        for (int k = 0; k < EDIMK; ++k) s += ea[k] * sw[k * HH + h];
        a_edge[(size_t)e * HH + h] = s;
    }
    atomicAdd(&deg[ei[EE + e]], 1);
}

// ---- one-block exclusive scan of deg -> rowptr ----
__global__ void k_scan(const int* __restrict__ deg, int* __restrict__ rowptr) {
    __shared__ int sd[1024];
    __shared__ int soff;
    int tid = threadIdx.x;
    if (tid == 0) { soff = 0; rowptr[0] = 0; }
    __syncthreads();
    for (int base = 0; base < NN; base += 1024) {
        int v = (base + tid < NN) ? deg[base + tid] : 0;
        sd[tid] = v;
        __syncthreads();
        for (int s = 1; s < 1024; s <<= 1) {
            int t2 = (tid >= s) ? sd[tid - s] : 0;
            __syncthreads();
            sd[tid] += t2;
            __syncthreads();
        }
        int incl = sd[tid];
        int off = soff;
        if (base + tid < NN) rowptr[base + tid + 1] = off + incl;
        __syncthreads();
        if (tid == 1023) soff = off + incl;
        __syncthreads();
    }
}

__global__ void k_scatter(const int* __restrict__ ei, const int* __restrict__ rowptr,
                          int* __restrict__ cursor, int* __restrict__ s_src,
                          int* __restrict__ s_eid) {
    int e = blockIdx.x * blockDim.x + threadIdx.x;
    if (e >= EE) return;
    int dst = ei[EE + e];
    int p = rowptr[dst] + atomicAdd(&cursor[dst], 1);
    s_src[p] = ei[e];
    s_eid[p] = e;
}

// ---- permute a_edge into CSR order ----
__global__ void k_permute(const int* __restrict__ s_eid, const float* __restrict__ a_edge,
                          float* __restrict__ ae_csr) {
    size_t t = (size_t)blockIdx.x * blockDim.x + threadIdx.x;
    if (t >= (size_t)EE * HH) return;
    ae_csr[t] = a_edge[(size_t)s_eid[t >> 3] * HH + (t & 7)];
}

// ---- self-loop a_edge = mean of incoming (coalesced CSR reads) ----
__global__ void k_selfmean(const int* __restrict__ rowptr, const float* __restrict__ ae_csr,
                           float* __restrict__ a_self) {
    int t = blockIdx.x * blockDim.x + threadIdx.x;
    if (t >= NN * HH) return;
    int n = t >> 3, h = t & 7;
    int k0 = rowptr[n], k1 = rowptr[n + 1];
    float s = 0.f;
    for (int k = k0; k < k1; ++k) s += ae_csr[(size_t)k * HH + h];
    int d = k1 - k0; if (d < 1) d = 1;
    a_self[t] = s / (float)d;
}

// ---- weight transpose + bf16 convert: dst[b][n][k] = src[b][k][n] ----
__global__ __launch_bounds__(1024) void k_trans(const float* __restrict__ src,
                                                ushort* __restrict__ dst, int K, int N) {
    __shared__ float s[32][33];
    const float* S = src + (size_t)blockIdx.z * K * N;
    ushort* D = dst + (size_t)blockIdx.z * K * N;
    int n0 = blockIdx.x * 32, k0 = blockIdx.y * 32;
    s[threadIdx.y][threadIdx.x] = S[(size_t)(k0 + threadIdx.y) * N + n0 + threadIdx.x];
    __syncthreads();
    D[(size_t)(n0 + threadIdx.y) * K + k0 + threadIdx.x] = f2b(s[threadIdx.x][threadIdx.y]);
}

// ---- m = x ; m_b = bf16(x) ----
__global__ void k_cvt(const float* __restrict__ x, float* __restrict__ m,
                      ushort* __restrict__ mb) {
    int t = blockIdx.x * blockDim.x + threadIdx.x;
    if (t >= NN * DD) return;
    float v = x[t];
    m[t] = v;
    mb[t] = f2b(v);
}

// ---- bf16 MFMA GEMM: C[M,Nc] = A[M,K] @ Bt[Nc,K]^T, 128x128 tile, BK=32 ----
// mode 0: fp32 out + bias; 1: bf16 out (no bias); 2: bf16 out + bias + relu
__global__ __launch_bounds__(256) void k_gemm_bf16(const ushort* __restrict__ A,
                                                   const ushort* __restrict__ Bt,
                                                   const float* __restrict__ bias,
                                                   void* __restrict__ Cout,
                                                   int Nc, int K, int mode) {
    __shared__ ushort As[128 * 32];
    __shared__ ushort Bs[128 * 32];
    int tid = threadIdx.x;
    int w = tid >> 6, lane = tid & 63;
    int tileM = blockIdx.y * 128, tileN = blockIdx.x * 128;
    // staging: wave w pass p covers LDS rows (p*4+w)*16..+15; lane -> row=lrow, 16B slot
    int lrow = lane >> 2, slot = lane & 3;
    int rA0 = w * 16 + lrow, rA1 = (w + 4) * 16 + lrow;
    int cA0 = (slot - (rA0 >> 1)) & 3;   // k-chunk swizzle: slot s holds chunk (s - (row>>1))&3
    int cA1 = (slot - (rA1 >> 1)) & 3;
    const ushort* gA0 = A + (size_t)(tileM + rA0) * K + cA0 * 8;
    const ushort* gA1 = A + (size_t)(tileM + rA1) * K + cA1 * 8;
    const ushort* gB0 = Bt + (size_t)(tileN + rA0) * K + cA0 * 8;
    const ushort* gB1 = Bt + (size_t)(tileN + rA1) * K + cA1 * 8;
    ushort* lA0 = As + w * 512;          // 1024 B per wave-instruction
    ushort* lA1 = As + (w + 4) * 512;
    ushort* lB0 = Bs + w * 512;
    ushort* lB1 = Bs + (w + 4) * 512;
    // fragment read offsets (swizzle-matched): 2-way banks only
    int wr = w >> 1, wc = w & 1;
    int fr = lane & 15, q = lane >> 4;
    int sf = (q + (fr >> 1)) & 3;
    const ushort* fA = As + (wr * 64 + fr) * 32 + sf * 8;
    const ushort* fB = Bs + (wc * 64 + fr) * 32 + sf * 8;
    floatx4 acc[4][4] = {};
    for (int k0 = 0; k0 < K; k0 += 32) {
        __syncthreads();
        gload_lds16(gA0 + k0, lA0);
        gload_lds16(gA1 + k0, lA1);
        gload_lds16(gB0 + k0, lB0);
        gload_lds16(gB1 + k0, lB1);
        __syncthreads();
        short8 af[4], bf[4];
#pragma unroll
        for (int i = 0; i < 4; ++i) af[i] = *(const short8*)(fA + i * 16 * 32);
#pragma unroll
        for (int j = 0; j < 4; ++j) bf[j] = *(const short8*)(fB + j * 16 * 32);
#pragma unroll
        for (int i = 0; i < 4; ++i)
#pragma unroll
            for (int j = 0; j < 4; ++j)
                acc[i][j] = __builtin_amdgcn_mfma_f32_16x16x32_bf16(af[i], bf[j], acc[i][j], 0, 0, 0);
    }
    // epilogue: C row = tileM + wr*64 + i*16 + q*4 + r ; col = tileN + wc*64 + j*16 + fr
    int rbase = tileM + wr * 64 + q * 4;
    int cbase = tileN + wc * 64 + fr;
#pragma unroll
    for (int j = 0; j < 4; ++j) {
        int col = cbase + j * 16;
        float bb = (mode != 1) ? bias[col] : 0.f;
#pragma unroll
        for (int i = 0; i < 4; ++i) {
            int row = rbase + i * 16;
#pragma unroll
            for (int r = 0; r < 4; ++r) {
                float v = acc[i][j][r] + bb;
                if (mode == 2 && v < 0.f) v = 0.f;
                if (mode == 0)
                    ((float*)Cout)[(size_t)(row + r) * Nc + col] = v;
                else
                    ((ushort*)Cout)[(size_t)(row + r) * Nc + col] = f2b(v);
            }
        }
    }
}

// ---- a_src/a_dst from bf16 x_proj ----
__global__ void k_srcdst(const ushort* __restrict__ xb, const float* __restrict__ att_src,
                         const float* __restrict__ att_dst, float* __restrict__ a_src,
                         float* __restrict__ a_dst) {
    __shared__ float ss[DD], sd[DD];
    int tid = threadIdx.x;
    if (tid < DD) { ss[tid] = att_src[tid]; sd[tid] = att_dst[tid]; }
    __syncthreads();
    int t = blockIdx.x * blockDim.x + tid;
    if (t >= NN * HH) return;
    int n = t >> 3, h = t & 7;
    const ushort* xp = xb + (size_t)n * DD + h * CC;
    float s1 = 0.f, s2 = 0.f;
#pragma unroll
    for (int c = 0; c < CC; c += 4) {
        ushort4 u = *(const ushort4*)(xp + c);
        float vx = b2f(u.x), vy = b2f(u.y), vz = b2f(u.z), vw = b2f(u.w);
        int b = h * CC + c;
        s1 += vx * ss[b] + vy * ss[b + 1] + vz * ss[b + 2] + vw * ss[b + 3];
        s2 += vx * sd[b] + vy * sd[b + 1] + vz * sd[b + 2] + vw * sd[b + 3];
    }
    a_src[t] = s1;
    a_dst[t] = s2;
}

// ---- fused: softmax-aggregate + bias + residual + LN1 -> m (fp32) + m_b (bf16) ----
__global__ __launch_bounds__(256) void k_agg(const ushort* __restrict__ xb,
                                             const float* __restrict__ a_src,
                                             const float* __restrict__ a_dst,
                                             const float* __restrict__ a_self,
                                             const int* __restrict__ rowptr,
                                             const int* __restrict__ s_src,
                                             const float* __restrict__ ae_csr,
                                             const float* __restrict__ bias,
                                             const float* __restrict__ gma,
                                             const float* __restrict__ bta,
                                             float* __restrict__ m,
                                             ushort* __restrict__ mb) {
    int wid = (blockIdx.x * blockDim.x + threadIdx.x) >> 6;
    int lane = threadIdx.x & 63;
    if (wid >= NN) return;
    int n = wid, h = lane >> 3, c4 = lane * 4;
    float adn = a_dst[n * HH + h];
    float al0 = a_src[n * HH + h] + adn + a_self[n * HH + h];
    al0 = al0 > 0.f ? al0 : NEG * al0;
    float w0 = __expf(al0);
    ushort4 xs = *(const ushort4*)(xb + (size_t)n * DD + c4);
    float den = w0;
    float ax = w0 * b2f(xs.x), ay = w0 * b2f(xs.y);
    float az = w0 * b2f(xs.z), aw = w0 * b2f(xs.w);
    int k0 = rowptr[n], k1 = rowptr[n + 1];
    int sNext = (k0 < k1) ? s_src[k0] : 0;
    for (int k = k0; k < k1; ++k) {
        int s = sNext;
        if (k + 1 < k1) sNext = s_src[k + 1];
        float al = a_src[(size_t)s * HH + h] + adn + ae_csr[(size_t)k * HH + h];
        al = al > 0.f ? al : NEG * al;
        float wv = __expf(al);
        den += wv;
        ushort4 v = *(const ushort4*)(xb + (size_t)s * DD + c4);
        ax += wv * b2f(v.x); ay += wv * b2f(v.y);
        az += wv * b2f(v.z); aw += wv * b2f(v.w);
    }
    float inv = 1.f / den;
    size_t base = (size_t)n * DD + c4;
    float4 mr = ld4(m + base);
    float4 b4 = ld4(bias + c4);
    float gx = ax * inv + b4.x + mr.x;
    float gy = ay * inv + b4.y + mr.y;
    float gz = az * inv + b4.z + mr.z;
    float gw = aw * inv + b4.w + mr.w;
    float s = gx + gy + gz + gw;
    for (int off = 32; off; off >>= 1) s += __shfl_xor(s, off, 64);
    float mu = s * (1.0f / DD);
    float dx = gx - mu, dy = gy - mu, dz = gz - mu, dw = gw - mu;
    float qv = dx * dx + dy * dy + dz * dz + dw * dw;
    for (int off = 32; off; off >>= 1) qv += __shfl_xor(qv, off, 64);
    float rs = rsqrtf(qv * (1.0f / DD) + LNEPS);
    float4 g4 = ld4(gma + c4), bb = ld4(bta + c4);
    float4 o;
    o.x = dx * rs * g4.x + bb.x; o.y = dy * rs * g4.y + bb.y;
    o.z = dz * rs * g4.z + bb.z; o.w = dw * rs * g4.w + bb.w;
    st4(m + base, o);
    ushort4 ob;
    ob.x = f2b(o.x); ob.y = f2b(o.y); ob.z = f2b(o.z); ob.w = f2b(o.w);
    *reinterpret_cast<ushort4*>(mb + base) = ob;
}

// ---- m = LN(a + m) ; also emit bf16 copy ----
__global__ __launch_bounds__(256) void k_addln2(const float* __restrict__ a,
                                                const float* __restrict__ gma,
                                                const float* __restrict__ bta,
                                                float* __restrict__ m,
                                                ushort* __restrict__ mb) {
    int wid = (blockIdx.x * blockDim.x + threadIdx.x) >> 6;
    int lane = threadIdx.x & 63;
    if (wid >= NN) return;
    size_t base = (size_t)wid * DD + lane * 4;
    float4 va = ld4(a + base), vb = ld4(m + base);
    float4 v;
    v.x = va.x + vb.x; v.y = va.y + vb.y; v.z = va.z + vb.z; v.w = va.w + vb.w;
    float s = v.x + v.y + v.z + v.w;
    for (int off = 32; off; off >>= 1) s += __shfl_xor(s, off, 64);
    float mu = s * (1.0f / DD);
    float4 d;
    d.x = v.x - mu; d.y = v.y - mu; d.z = v.z - mu; d.w = v.w - mu;
    float qv = d.x * d.x + d.y * d.y + d.z * d.z + d.w * d.w;
    for (int off = 32; off; off >>= 1) qv += __shfl_xor(qv, off, 64);
    float rs = rsqrtf(qv * (1.0f / DD) + LNEPS);
    float4 g4 = ld4(gma + lane * 4), b4 = ld4(bta + lane * 4);
    float4 o;
    o.x = d.x * rs * g4.x + b4.x; o.y = d.y * rs * g4.y + b4.y;
    o.z = d.z * rs * g4.z + b4.z; o.w = d.w * rs * g4.w + b4.w;
    st4(m + base, o);
    ushort4 ob;
    ob.x = f2b(o.x); ob.y = f2b(o.y); ob.z = f2b(o.z); ob.w = f2b(o.w);
    *reinterpret_cast<ushort4*>(mb + base) = ob;
}

extern "C" void kernel_launch(void* const* d_in, const int* in_sizes, int n_in,
                              void* d_out, int out_size, void* d_ws, size_t ws_size,
                              hipStream_t stream) {
    const float* x        = (const float*)d_in[0];
    const int*   ei       = (const int*)d_in[1];
    const float* edge_attr= (const float*)d_in[2];
    const float* W        = (const float*)d_in[3];
    const float* att_src  = (const float*)d_in[4];
    const float* att_dst  = (const float*)d_in[5];
    const float* att_edge = (const float*)d_in[6];
    const float* W_edge   = (const float*)d_in[7];
    const float* bias     = (const float*)d_in[8];
    const float* ffn_w1   = (const float*)d_in[9];
    const float* ffn_b1   = (const float*)d_in[10];
    const float* ffn_w2   = (const float*)d_in[11];
    const float* ffn_b2   = (const float*)d_in[12];
    const float* ln1_g    = (const float*)d_in[13];
    const float* ln1_b    = (const float*)d_in[14];
    const float* ln2_g    = (const float*)d_in[15];
    const float* ln2_b    = (const float*)d_in[16];
    float* m = (float*)d_out;

    char* wp = (char*)d_ws;
    auto alloc = [&](size_t bytes) -> char* {
        char* p = wp;
        wp += (bytes + 255) & ~(size_t)255;
        return p;
    };
    float*  a_edge = (float*)alloc((size_t)EE * HH * 4);
    float*  ae_csr = (float*)alloc((size_t)EE * HH * 4);
    float*  a_self = (float*)alloc((size_t)NN * HH * 4);
    float*  a_src  = (float*)alloc((size_t)NN * HH * 4);
    float*  a_dst  = (float*)alloc((size_t)NN * HH * 4);
    int*    deg    = (int*)alloc((size_t)NN * 4);
    int*    rowptr = (int*)alloc((size_t)(NN + 1) * 4);
    int*    cursor = (int*)alloc((size_t)NN * 4);
    int*    s_src  = (int*)alloc((size_t)EE * 4);
    int*    s_eid  = (int*)alloc((size_t)EE * 4);
    float*  w_eh   = (float*)alloc((size_t)EDIMK * HH * 4);
    ushort* Wt     = (ushort*)alloc((size_t)DD * DD * 2);
    ushort* w1t    = (ushort*)alloc((size_t)LL * DD * HID * 2);
    ushort* w2t    = (ushort*)alloc((size_t)LL * HID * DD * 2);
    ushort* xprojb = (ushort*)alloc((size_t)MP * DD * 2);
    ushort* m_b    = (ushort*)alloc((size_t)MP * DD * 2);
    float*  gbuf   = (float*)alloc((size_t)MP * DD * 4);
    size_t used = (size_t)(wp - (char*)d_ws);
    size_t avail = ws_size > used ? ws_size - used : 0;
    size_t maxrows = avail / ((size_t)HID * 2);
    int chunkP = (int)((maxrows / 128) * 128);
    if (chunkP < 128) chunkP = 128;
    if (chunkP > MP) chunkP = MP;
    ushort* h1b = (ushort*)wp;

    hipMemsetAsync(deg, 0, (size_t)NN * 4, stream);
    hipMemsetAsync(cursor, 0, (size_t)NN * 4, stream);

    // layer-invariant precompute
    k_weh<<<1, 128, 0, stream>>>(W_edge, att_edge, w_eh);
    k_edge_pre<<<(EE + 255) / 256, 256, 0, stream>>>(edge_attr, ei, w_eh, a_edge, deg);
    k_scan<<<1, 1024, 0, stream>>>(deg, rowptr);
    k_scatter<<<(EE + 255) / 256, 256, 0, stream>>>(ei, rowptr, cursor, s_src, s_eid);
    k_permute<<<(EE * HH + 255) / 256, 256, 0, stream>>>(s_eid, a_edge, ae_csr);
    k_selfmean<<<(NN * HH + 255) / 256, 256, 0, stream>>>(rowptr, ae_csr, a_self);
    // weights -> bf16 transposed
    k_trans<<<dim3(DD / 32, DD / 32, 1), dim3(32, 32), 0, stream>>>(W, Wt, DD, DD);
    k_trans<<<dim3(HID / 32, DD / 32, LL), dim3(32, 32), 0, stream>>>(ffn_w1, w1t, DD, HID);
    k_trans<<<dim3(DD / 32, HID / 32, LL), dim3(32, 32), 0, stream>>>(ffn_w2, w2t, HID, DD);
    // m = x, m_b = bf16(x)
    k_cvt<<<(NN * DD + 255) / 256, 256, 0, stream>>>(x, m, m_b);

    for (int i = 0; i < LL; ++i) {
        // x_projb = m_b @ W (bf16 out)
        k_gemm_bf16<<<dim3(DD / 128, MP / 128), 256, 0, stream>>>(m_b, Wt, nullptr, xprojb, DD, DD, 1);
        k_srcdst<<<(NN * HH + 255) / 256, 256, 0, stream>>>(xprojb, att_src, att_dst, a_src, a_dst);
        k_agg<<<(NN * 64 + 255) / 256, 256, 0, stream>>>(xprojb, a_src, a_dst, a_self, rowptr,
                                                         s_src, ae_csr, bias,
                                                         ln1_g + i * DD, ln1_b + i * DD, m, m_b);
        for (int r0 = 0; r0 < MP; r0 += chunkP) {
            int rows = (MP - r0) < chunkP ? (MP - r0) : chunkP;
            k_gemm_bf16<<<dim3(HID / 128, rows / 128), 256, 0, stream>>>(
                m_b + (size_t)r0 * DD, w1t + (size_t)i * DD * HID,
                ffn_b1 + (size_t)i * HID, h1b, HID, DD, 2);
            k_gemm_bf16<<<dim3(DD / 128, rows / 128), 256, 0, stream>>>(
                h1b, w2t + (size_t)i * HID * DD,
                ffn_b2 + (size_t)i * DD, gbuf + (size_t)r0 * DD, DD, HID, 0);
        }
        k_addln2<<<(NN * 64 + 255) / 256, 256, 0, stream>>>(gbuf, ln2_g + i * DD, ln2_b + i * DD, m, m_b);
    }
}

// Round 3
// 2000.074 us; speedup vs baseline: 4.9585x; 1.1428x over previous
//
#include <hip/hip_runtime.h>
#include <math.h>

#define NN 50000
#define MP 50048           // NN padded to multiple of 128
#define EE 800000
#define DD 256
#define HH 8
#define CC 32
#define EDIMK 16
#define LL 6
#define HID 1024
#define NEG 0.2f
#define LNEPS 1e-5f
#define NPARTS ((NN + 255) / 256)

using short8   = __attribute__((ext_vector_type(8))) short;
using ushort8  = __attribute__((ext_vector_type(8))) unsigned short;
using floatx4  = __attribute__((ext_vector_type(4))) float;

static __device__ __forceinline__ float4 ld4(const float* p) {
    return *reinterpret_cast<const float4*>(p);
}
static __device__ __forceinline__ void st4(float* p, float4 v) {
    *reinterpret_cast<float4*>(p) = v;
}
static __device__ __forceinline__ float b2f(unsigned short u) {
    union { unsigned int i; float f; } v; v.i = ((unsigned int)u) << 16; return v.f;
}
static __device__ __forceinline__ unsigned short f2b(float f) {
    union { float f; unsigned int i; } v; v.f = f;
    unsigned int r = (v.i + 0x7fffu + ((v.i >> 16) & 1u)) >> 16;
    return (unsigned short)r;
}
static __device__ __forceinline__ void gload_lds16(const ushort* g, ushort* l) {
    __builtin_amdgcn_global_load_lds((const __attribute__((address_space(1))) void*)g,
                                     (__attribute__((address_space(3))) void*)l, 16, 0, 0);
}

// ---- w_eh[k][h] = sum_c W_edge[k, h*32+c] * att_edge[h, c] ----
__global__ void k_weh(const float* __restrict__ W_edge, const float* __restrict__ att_edge,
                      float* __restrict__ w_eh) {
    int t = threadIdx.x;
    if (t < EDIMK * HH) {
        int k = t >> 3, h = t & 7;
        float s = 0.f;
        for (int c = 0; c < CC; ++c) s += W_edge[k * DD + h * CC + c] * att_edge[h * CC + c];
        w_eh[t] = s;
    }
}

// ---- per-edge a_edge + deg (no float atomics) ----
__global__ void k_edge_pre(const float* __restrict__ edge_attr, const int* __restrict__ ei,
                           const float* __restrict__ w_eh, float* __restrict__ a_edge,
                           int* __restrict__ deg) {
    __shared__ float sw[EDIMK * HH];
    if (threadIdx.x < EDIMK * HH) sw[threadIdx.x] = w_eh[threadIdx.x];
    __syncthreads();
    int e = blockIdx.x * blockDim.x + threadIdx.x;
    if (e >= EE) return;
    float ea[EDIMK];
#pragma unroll
    for (int k4 = 0; k4 < EDIMK; k4 += 4) {
        float4 v = ld4(edge_attr + (size_t)e * EDIMK + k4);
        ea[k4] = v.x; ea[k4 + 1] = v.y; ea[k4 + 2] = v.z; ea[k4 + 3] = v.w;
    }
#pragma unroll
    for (int h = 0; h < HH; ++h) {
        float s = 0.f;
#pragma unroll
        for (int k = 0; k < EDIMK; ++k) s += ea[k] * sw[k * HH + h];
        a_edge[(size_t)e * HH + h] = s;
    }
    atomicAdd(&deg[ei[EE + e]], 1);
}

// ---- 3-phase scan: deg -> rowptr (exclusive) ----
__global__ __launch_bounds__(256) void k_scan1(const int* __restrict__ deg,
                                               int* __restrict__ rowptr,
                                               int* __restrict__ part) {
    __shared__ int wsum[4];
    int tid = threadIdx.x, wid = tid >> 6, lane = tid & 63;
    int g = blockIdx.x * 256 + tid;
    int v = (g < NN) ? deg[g] : 0;
    int s = v;
#pragma unroll
    for (int off = 1; off < 64; off <<= 1) {
        int t = __shfl_up(s, off, 64);
        if (lane >= off) s += t;
    }
    if (lane == 63) wsum[wid] = s;
    __syncthreads();
    int woff = 0;
    for (int i = 0; i < wid; ++i) woff += wsum[i];
    s += woff;
    if (g < NN) rowptr[g + 1] = s;
    if (tid == 255) part[blockIdx.x] = s;
}
__global__ __launch_bounds__(256) void k_scan2(int* __restrict__ part) {
    __shared__ int wsum[4];
    int tid = threadIdx.x, wid = tid >> 6, lane = tid & 63;
    int v = (tid < NPARTS) ? part[tid] : 0;
    int s = v;
#pragma unroll
    for (int off = 1; off < 64; off <<= 1) {
        int t = __shfl_up(s, off, 64);
        if (lane >= off) s += t;
    }
    if (lane == 63) wsum[wid] = s;
    __syncthreads();
    int woff = 0;
    for (int i = 0; i < wid; ++i) woff += wsum[i];
    s += woff;
    if (tid < NPARTS) part[tid] = s - v;   // exclusive
}
__global__ __launch_bounds__(256) void k_scan3(int* __restrict__ rowptr,
                                               const int* __restrict__ part) {
    int g = blockIdx.x * 256 + threadIdx.x;
    if (g == 0) rowptr[0] = 0;
    if (g < NN) rowptr[g + 1] += part[blockIdx.x];
}

__global__ void k_scatter(const int* __restrict__ ei, const int* __restrict__ rowptr,
                          int* __restrict__ cursor, int* __restrict__ s_src,
                          int* __restrict__ s_eid) {
    int e = blockIdx.x * blockDim.x + threadIdx.x;
    if (e >= EE) return;
    int dst = ei[EE + e];
    int p = rowptr[dst] + atomicAdd(&cursor[dst], 1);
    s_src[p] = ei[e];
    s_eid[p] = e;
}

// ---- permute a_edge into CSR order ----
__global__ void k_permute(const int* __restrict__ s_eid, const float* __restrict__ a_edge,
                          float* __restrict__ ae_csr) {
    size_t t = (size_t)blockIdx.x * blockDim.x + threadIdx.x;
    if (t >= (size_t)EE * HH) return;
    ae_csr[t] = a_edge[(size_t)s_eid[t >> 3] * HH + (t & 7)];
}

// ---- self-loop a_edge = mean of incoming ----
__global__ void k_selfmean(const int* __restrict__ rowptr, const float* __restrict__ ae_csr,
                           float* __restrict__ a_self) {
    int t = blockIdx.x * blockDim.x + threadIdx.x;
    if (t >= NN * HH) return;
    int n = t >> 3, h = t & 7;
    int k0 = rowptr[n], k1 = rowptr[n + 1];
    float s = 0.f;
    for (int k = k0; k < k1; ++k) s += ae_csr[(size_t)k * HH + h];
    int d = k1 - k0; if (d < 1) d = 1;
    a_self[t] = s / (float)d;
}

// ---- weight transpose + bf16 convert: dst[b][n][k] = src[b][k][n] ----
__global__ __launch_bounds__(1024) void k_trans(const float* __restrict__ src,
                                                ushort* __restrict__ dst, int K, int N) {
    __shared__ float s[32][33];
    const float* S = src + (size_t)blockIdx.z * K * N;
    ushort* D = dst + (size_t)blockIdx.z * K * N;
    int n0 = blockIdx.x * 32, k0 = blockIdx.y * 32;
    s[threadIdx.y][threadIdx.x] = S[(size_t)(k0 + threadIdx.y) * N + n0 + threadIdx.x];
    __syncthreads();
    D[(size_t)(n0 + threadIdx.y) * K + k0 + threadIdx.x] = f2b(s[threadIdx.x][threadIdx.y]);
}

// ---- m = x ; m_b = bf16(x) ----
__global__ void k_cvt(const float* __restrict__ x, float* __restrict__ m,
                      ushort* __restrict__ mb) {
    int t = blockIdx.x * blockDim.x + threadIdx.x;
    if (t >= NN * DD) return;
    float v = x[t];
    m[t] = v;
    mb[t] = f2b(v);
}

// ---- bf16 MFMA GEMM: C[M,Nc] = A[M,K] @ Bt[Nc,K]^T, 128x128 tile, BK=64 ----
// mode 0: fp32 out + bias; 1: bf16 out (no bias); 2: bf16 + bias + relu; 3: bf16 + bias
__global__ __launch_bounds__(256) void k_gemm_bf16(const ushort* __restrict__ A,
                                                   const ushort* __restrict__ Bt,
                                                   const float* __restrict__ bias,
                                                   void* __restrict__ Cout,
                                                   int Nc, int K, int mode) {
    __shared__ ushort As[128 * 64];
    __shared__ ushort Bs[128 * 64];
    int tid = threadIdx.x;
    int w = tid >> 6, lane = tid & 63;
    int tileM = blockIdx.y * 128, tileN = blockIdx.x * 128;
    // staging: pass p, wave w, lane -> 16B chunk c = (p*4+w)*64+lane of the 128x64 tile
    // row = c>>3, slot = c&7; global source slot = slot ^ (row&7) (k-chunk swizzle)
    const ushort* gA[4]; const ushort* gB[4];
    ushort* lA[4]; ushort* lB[4];
#pragma unroll
    for (int p = 0; p < 4; ++p) {
        int c = (p * 4 + w) * 64 + lane;
        int row = c >> 3, slot = c & 7;
        int gs = slot ^ (row & 7);
        gA[p] = A + (size_t)(tileM + row) * K + gs * 8;
        gB[p] = Bt + (size_t)(tileN + row) * K + gs * 8;
        lA[p] = As + (size_t)c * 8;
        lB[p] = Bs + (size_t)c * 8;
    }
    int wr = w >> 1, wc = w & 1;
    int fr = lane & 15, q = lane >> 4;
    floatx4 acc[4][4] = {};
    for (int k0 = 0; k0 < K; k0 += 64) {
        __syncthreads();
#pragma unroll
        for (int p = 0; p < 4; ++p) gload_lds16(gA[p] + k0, lA[p]);
#pragma unroll
        for (int p = 0; p < 4; ++p) gload_lds16(gB[p] + k0, lB[p]);
        __syncthreads();
#pragma unroll
        for (int kc = 0; kc < 2; ++kc) {
            int ps = ((kc * 4 + q) ^ (fr & 7)) * 8;   // physical slot (elements)
            short8 af[4], bf[4];
#pragma unroll
            for (int i = 0; i < 4; ++i)
                af[i] = *(const short8*)(As + (wr * 64 + i * 16 + fr) * 64 + ps);
#pragma unroll
            for (int j = 0; j < 4; ++j)
                bf[j] = *(const short8*)(Bs + (wc * 64 + j * 16 + fr) * 64 + ps);
#pragma unroll
            for (int i = 0; i < 4; ++i)
#pragma unroll
                for (int j = 0; j < 4; ++j)
                    acc[i][j] = __builtin_amdgcn_mfma_f32_16x16x32_bf16(af[i], bf[j], acc[i][j], 0, 0, 0);
        }
    }
    int rbase = tileM + wr * 64 + q * 4;
    int cbase = tileN + wc * 64 + fr;
#pragma unroll
    for (int j = 0; j < 4; ++j) {
        int col = cbase + j * 16;
        float bb = (mode != 1) ? bias[col] : 0.f;
#pragma unroll
        for (int i = 0; i < 4; ++i) {
            int row = rbase + i * 16;
#pragma unroll
            for (int r = 0; r < 4; ++r) {
                float v = acc[i][j][r] + bb;
                if (mode == 2 && v < 0.f) v = 0.f;
                if (mode == 0)
                    ((float*)Cout)[(size_t)(row + r) * Nc + col] = v;
                else
                    ((ushort*)Cout)[(size_t)(row + r) * Nc + col] = f2b(v);
            }
        }
    }
}

// ---- a_src/a_dst from bf16 x_proj ----
__global__ void k_srcdst(const ushort* __restrict__ xb, const float* __restrict__ att_src,
                         const float* __restrict__ att_dst, float* __restrict__ a_src,
                         float* __restrict__ a_dst) {
    __shared__ float ss[DD], sd[DD];
    int tid = threadIdx.x;
    if (tid < DD) { ss[tid] = att_src[tid]; sd[tid] = att_dst[tid]; }
    __syncthreads();
    int t = blockIdx.x * blockDim.x + tid;
    if (t >= NN * HH) return;
    int n = t >> 3, h = t & 7;
    const ushort* xp = xb + (size_t)n * DD + h * CC;
    float s1 = 0.f, s2 = 0.f;
#pragma unroll
    for (int c = 0; c < CC; c += 4) {
        ushort4 u = *(const ushort4*)(xp + c);
        float vx = b2f(u.x), vy = b2f(u.y), vz = b2f(u.z), vw = b2f(u.w);
        int b = h * CC + c;
        s1 += vx * ss[b] + vy * ss[b + 1] + vz * ss[b + 2] + vw * ss[b + 3];
        s2 += vx * sd[b] + vy * sd[b + 1] + vz * sd[b + 2] + vw * sd[b + 3];
    }
    a_src[t] = s1;
    a_dst[t] = s2;
}

// ---- fused softmax-aggregate + bias + residual + LN1 : 2 nodes/wave, 8ch/lane ----
__global__ __launch_bounds__(256) void k_agg(const ushort* __restrict__ xb,
                                             const float* __restrict__ a_src,
                                             const float* __restrict__ a_dst,
                                             const float* __restrict__ a_self,
                                             const int* __restrict__ rowptr,
                                             const int* __restrict__ s_src,
                                             const float* __restrict__ ae_csr,
                                             const float* __restrict__ bias,
                                             const float* __restrict__ gma,
                                             const float* __restrict__ bta,
                                             float* __restrict__ m,
                                             ushort* __restrict__ mb) {
    int wid = (blockIdx.x * blockDim.x + threadIdx.x) >> 6;
    int lane = threadIdx.x & 63;
    int n = wid * 2 + (lane >> 5);
    if (n >= NN) return;
    int hl = lane & 31, h = hl >> 2, c8 = hl * 8;
    float adn = a_dst[n * HH + h];
    float al0 = a_src[n * HH + h] + adn + a_self[n * HH + h];
    al0 = al0 > 0.f ? al0 : NEG * al0;
    float w0 = __expf(al0);
    ushort8 xs = *(const ushort8*)(xb + (size_t)n * DD + c8);
    float acc[8];
#pragma unroll
    for (int i = 0; i < 8; ++i) acc[i] = w0 * b2f(xs[i]);
    float den = w0;
    int k = rowptr[n], k1 = rowptr[n + 1];
    for (; k + 1 < k1; k += 2) {
        int s0 = s_src[k], s1 = s_src[k + 1];
        float t0 = a_src[(size_t)s0 * HH + h] + adn + ae_csr[(size_t)k * HH + h];
        float t1 = a_src[(size_t)s1 * HH + h] + adn + ae_csr[(size_t)(k + 1) * HH + h];
        t0 = t0 > 0.f ? t0 : NEG * t0;
        t1 = t1 > 0.f ? t1 : NEG * t1;
        float wv0 = __expf(t0), wv1 = __expf(t1);
        ushort8 v0 = *(const ushort8*)(xb + (size_t)s0 * DD + c8);
        ushort8 v1 = *(const ushort8*)(xb + (size_t)s1 * DD + c8);
        den += wv0 + wv1;
#pragma unroll
        for (int i = 0; i < 8; ++i) acc[i] += wv0 * b2f(v0[i]) + wv1 * b2f(v1[i]);
    }
    if (k < k1) {
        int s0 = s_src[k];
        float t0 = a_src[(size_t)s0 * HH + h] + adn + ae_csr[(size_t)k * HH + h];
        t0 = t0 > 0.f ? t0 : NEG * t0;
        float wv0 = __expf(t0);
        ushort8 v0 = *(const ushort8*)(xb + (size_t)s0 * DD + c8);
        den += wv0;
#pragma unroll
        for (int i = 0; i < 8; ++i) acc[i] += wv0 * b2f(v0[i]);
    }
    float inv = 1.f / den;
    size_t base = (size_t)n * DD + c8;
    float4 mr0 = ld4(m + base), mr1 = ld4(m + base + 4);
    float4 b0 = ld4(bias + c8), b1 = ld4(bias + c8 + 4);
    float g[8];
    g[0] = acc[0] * inv + b0.x + mr0.x; g[1] = acc[1] * inv + b0.y + mr0.y;
    g[2] = acc[2] * inv + b0.z + mr0.z; g[3] = acc[3] * inv + b0.w + mr0.w;
    g[4] = acc[4] * inv + b1.x + mr1.x; g[5] = acc[5] * inv + b1.y + mr1.y;
    g[6] = acc[6] * inv + b1.z + mr1.z; g[7] = acc[7] * inv + b1.w + mr1.w;
    float s = 0.f;
#pragma unroll
    for (int i = 0; i < 8; ++i) s += g[i];
#pragma unroll
    for (int off = 16; off; off >>= 1) s += __shfl_xor(s, off, 64);
    float mu = s * (1.0f / DD);
    float qv = 0.f;
#pragma unroll
    for (int i = 0; i < 8; ++i) { g[i] -= mu; qv += g[i] * g[i]; }
#pragma unroll
    for (int off = 16; off; off >>= 1) qv += __shfl_xor(qv, off, 64);
    float rs = rsqrtf(qv * (1.0f / DD) + LNEPS);
    float4 g0 = ld4(gma + c8), g1 = ld4(gma + c8 + 4);
    float4 bb0 = ld4(bta + c8), bb1 = ld4(bta + c8 + 4);
    float o[8];
    o[0] = g[0] * rs * g0.x + bb0.x; o[1] = g[1] * rs * g0.y + bb0.y;
    o[2] = g[2] * rs * g0.z + bb0.z; o[3] = g[3] * rs * g0.w + bb0.w;
    o[4] = g[4] * rs * g1.x + bb1.x; o[5] = g[5] * rs * g1.y + bb1.y;
    o[6] = g[6] * rs * g1.z + bb1.z; o[7] = g[7] * rs * g1.w + bb1.w;
    st4(m + base, make_float4(o[0], o[1], o[2], o[3]));
    st4(m + base + 4, make_float4(o[4], o[5], o[6], o[7]));
    ushort8 ob;
#pragma unroll
    for (int i = 0; i < 8; ++i) ob[i] = f2b(o[i]);
    *reinterpret_cast<ushort8*>(mb + base) = ob;
}

// ---- m = LN(gbuf_bf16 + m) ; emit bf16 copy ----
__global__ __launch_bounds__(256) void k_addln2(const ushort* __restrict__ a,
                                                const float* __restrict__ gma,
                                                const float* __restrict__ bta,
                                                float* __restrict__ m,
                                                ushort* __restrict__ mb) {
    int wid = (blockIdx.x * blockDim.x + threadIdx.x) >> 6;
    int lane = threadIdx.x & 63;
    if (wid >= NN) return;
    size_t base = (size_t)wid * DD + lane * 4;
    ushort4 ua = *(const ushort4*)(a + base);
    float4 vb = ld4(m + base);
    float4 v;
    v.x = b2f(ua.x) + vb.x; v.y = b2f(ua.y) + vb.y;
    v.z = b2f(ua.z) + vb.z; v.w = b2f(ua.w) + vb.w;
    float s = v.x + v.y + v.z + v.w;
    for (int off = 32; off; off >>= 1) s += __shfl_xor(s, off, 64);
    float mu = s * (1.0f / DD);
    float4 d;
    d.x = v.x - mu; d.y = v.y - mu; d.z = v.z - mu; d.w = v.w - mu;
    float qv = d.x * d.x + d.y * d.y + d.z * d.z + d.w * d.w;
    for (int off = 32; off; off >>= 1) qv += __shfl_xor(qv, off, 64);
    float rs = rsqrtf(qv * (1.0f / DD) + LNEPS);
    float4 g4 = ld4(gma + lane * 4), b4 = ld4(bta + lane * 4);
    float4 o;
    o.x = d.x * rs * g4.x + b4.x; o.y = d.y * rs * g4.y + b4.y;
    o.z = d.z * rs * g4.z + b4.z; o.w = d.w * rs * g4.w + b4.w;
    st4(m + base, o);
    ushort4 ob;
    ob.x = f2b(o.x); ob.y = f2b(o.y); ob.z = f2b(o.z); ob.w = f2b(o.w);
    *reinterpret_cast<ushort4*>(mb + base) = ob;
}

extern "C" void kernel_launch(void* const* d_in, const int* in_sizes, int n_in,
                              void* d_out, int out_size, void* d_ws, size_t ws_size,
                              hipStream_t stream) {
    const float* x        = (const float*)d_in[0];
    const int*   ei       = (const int*)d_in[1];
    const float* edge_attr= (const float*)d_in[2];
    const float* W        = (const float*)d_in[3];
    const float* att_src  = (const float*)d_in[4];
    const float* att_dst  = (const float*)d_in[5];
    const float* att_edge = (const float*)d_in[6];
    const float* W_edge   = (const float*)d_in[7];
    const float* bias     = (const float*)d_in[8];
    const float* ffn_w1   = (const float*)d_in[9];
    const float* ffn_b1   = (const float*)d_in[10];
    const float* ffn_w2   = (const float*)d_in[11];
    const float* ffn_b2   = (const float*)d_in[12];
    const float* ln1_g    = (const float*)d_in[13];
    const float* ln1_b    = (const float*)d_in[14];
    const float* ln2_g    = (const float*)d_in[15];
    const float* ln2_b    = (const float*)d_in[16];
    float* m = (float*)d_out;

    char* wp = (char*)d_ws;
    auto alloc = [&](size_t bytes) -> char* {
        char* p = wp;
        wp += (bytes + 255) & ~(size_t)255;
        return p;
    };
    float*  a_edge = (float*)alloc((size_t)EE * HH * 4);
    float*  ae_csr = (float*)alloc((size_t)EE * HH * 4);
    float*  a_self = (float*)alloc((size_t)NN * HH * 4);
    float*  a_src  = (float*)alloc((size_t)NN * HH * 4);
    float*  a_dst  = (float*)alloc((size_t)NN * HH * 4);
    int*    deg    = (int*)alloc((size_t)NN * 4);
    int*    rowptr = (int*)alloc((size_t)(NN + 1) * 4);
    int*    cursor = (int*)alloc((size_t)NN * 4);
    int*    part   = (int*)alloc((size_t)NPARTS * 4);
    int*    s_src  = (int*)alloc((size_t)EE * 4);
    int*    s_eid  = (int*)alloc((size_t)EE * 4);
    float*  w_eh   = (float*)alloc((size_t)EDIMK * HH * 4);
    ushort* Wt     = (ushort*)alloc((size_t)DD * DD * 2);
    ushort* w1t    = (ushort*)alloc((size_t)LL * DD * HID * 2);
    ushort* w2t    = (ushort*)alloc((size_t)LL * HID * DD * 2);
    ushort* xprojb = (ushort*)alloc((size_t)MP * DD * 2);
    ushort* m_b    = (ushort*)alloc((size_t)MP * DD * 2);
    ushort* gbuf   = (ushort*)alloc((size_t)MP * DD * 2);
    size_t used = (size_t)(wp - (char*)d_ws);
    size_t avail = ws_size > used ? ws_size - used : 0;
    size_t maxrows = avail / ((size_t)HID * 2);
    int chunkP = (int)((maxrows / 128) * 128);
    if (chunkP < 128) chunkP = 128;
    if (chunkP > MP) chunkP = MP;
    ushort* h1b = (ushort*)wp;

    hipMemsetAsync(deg, 0, (size_t)NN * 4, stream);
    hipMemsetAsync(cursor, 0, (size_t)NN * 4, stream);

    // layer-invariant precompute
    k_weh<<<1, 128, 0, stream>>>(W_edge, att_edge, w_eh);
    k_edge_pre<<<(EE + 255) / 256, 256, 0, stream>>>(edge_attr, ei, w_eh, a_edge, deg);
    k_scan1<<<NPARTS, 256, 0, stream>>>(deg, rowptr, part);
    k_scan2<<<1, 256, 0, stream>>>(part);
    k_scan3<<<NPARTS, 256, 0, stream>>>(rowptr, part);
    k_scatter<<<(EE + 255) / 256, 256, 0, stream>>>(ei, rowptr, cursor, s_src, s_eid);
    k_permute<<<(EE * HH + 255) / 256, 256, 0, stream>>>(s_eid, a_edge, ae_csr);
    k_selfmean<<<(NN * HH + 255) / 256, 256, 0, stream>>>(rowptr, ae_csr, a_self);
    // weights -> bf16 transposed
    k_trans<<<dim3(DD / 32, DD / 32, 1), dim3(32, 32), 0, stream>>>(W, Wt, DD, DD);
    k_trans<<<dim3(HID / 32, DD / 32, LL), dim3(32, 32), 0, stream>>>(ffn_w1, w1t, DD, HID);
    k_trans<<<dim3(DD / 32, HID / 32, LL), dim3(32, 32), 0, stream>>>(ffn_w2, w2t, HID, DD);
    // m = x, m_b = bf16(x)
    k_cvt<<<(NN * DD + 255) / 256, 256, 0, stream>>>(x, m, m_b);

    for (int i = 0; i < LL; ++i) {
        k_gemm_bf16<<<dim3(DD / 128, MP / 128), 256, 0, stream>>>(m_b, Wt, nullptr, xprojb, DD, DD, 1);
        k_srcdst<<<(NN * HH + 255) / 256, 256, 0, stream>>>(xprojb, att_src, att_dst, a_src, a_dst);
        k_agg<<<((NN + 1) / 2 * 64 + 255) / 256, 256, 0, stream>>>(xprojb, a_src, a_dst, a_self,
                                                                   rowptr, s_src, ae_csr, bias,
                                                                   ln1_g + i * DD, ln1_b + i * DD, m, m_b);
        for (int r0 = 0; r0 < MP; r0 += chunkP) {
            int rows = (MP - r0) < chunkP ? (MP - r0) : chunkP;
            k_gemm_bf16<<<dim3(HID / 128, rows / 128), 256, 0, stream>>>(
                m_b + (size_t)r0 * DD, w1t + (size_t)i * DD * HID,
                ffn_b1 + (size_t)i * HID, h1b, HID, DD, 2);
            k_gemm_bf16<<<dim3(DD / 128, rows / 128), 256, 0, stream>>>(
                h1b, w2t + (size_t)i * HID * DD,
                ffn_b2 + (size_t)i * DD, gbuf + (size_t)r0 * DD, DD, HID, 3);
        }
        k_addln2<<<(NN * 64 + 255) / 256, 256, 0, stream>>>(gbuf, ln2_g + i * DD, ln2_b + i * DD, m, m_b);
    }
}

// Round 4
// 1857.420 us; speedup vs baseline: 5.3394x; 1.0768x over previous
//
#include <hip/hip_runtime.h>
#include <math.h>

#define NN 50000
#define MP 50048           // NN padded to multiple of 128
#define EE 800000
#define DD 256
#define HH 8
#define CC 32
#define EDIMK 16
#define LL 6
#define HID 1024
#define NEG 0.2f
#define LNEPS 1e-5f
#define NPARTS ((NN + 255) / 256)

using short8   = __attribute__((ext_vector_type(8))) short;
using ushort8  = __attribute__((ext_vector_type(8))) unsigned short;
using floatx4  = __attribute__((ext_vector_type(4))) float;

static __device__ __forceinline__ float4 ld4(const float* p) {
    return *reinterpret_cast<const float4*>(p);
}
static __device__ __forceinline__ void st4(float* p, float4 v) {
    *reinterpret_cast<float4*>(p) = v;
}
static __device__ __forceinline__ float b2f(unsigned short u) {
    union { unsigned int i; float f; } v; v.i = ((unsigned int)u) << 16; return v.f;
}
static __device__ __forceinline__ unsigned short f2b(float f) {
    union { float f; unsigned int i; } v; v.f = f;
    unsigned int r = (v.i + 0x7fffu + ((v.i >> 16) & 1u)) >> 16;
    return (unsigned short)r;
}
static __device__ __forceinline__ void gload_lds16(const ushort* g, ushort* l) {
    __builtin_amdgcn_global_load_lds((const __attribute__((address_space(1))) void*)g,
                                     (__attribute__((address_space(3))) void*)l, 16, 0, 0);
}

// ---- w_eh[k][h] = sum_c W_edge[k, h*32+c] * att_edge[h, c] ----
__global__ void k_weh(const float* __restrict__ W_edge, const float* __restrict__ att_edge,
                      float* __restrict__ w_eh) {
    int t = threadIdx.x;
    if (t < EDIMK * HH) {
        int k = t >> 3, h = t & 7;
        float s = 0.f;
        for (int c = 0; c < CC; ++c) s += W_edge[k * DD + h * CC + c] * att_edge[h * CC + c];
        w_eh[t] = s;
    }
}

// ---- per-edge a_edge + deg (no float atomics) ----
__global__ void k_edge_pre(const float* __restrict__ edge_attr, const int* __restrict__ ei,
                           const float* __restrict__ w_eh, float* __restrict__ a_edge,
                           int* __restrict__ deg) {
    __shared__ float sw[EDIMK * HH];
    if (threadIdx.x < EDIMK * HH) sw[threadIdx.x] = w_eh[threadIdx.x];
    __syncthreads();
    int e = blockIdx.x * blockDim.x + threadIdx.x;
    if (e >= EE) return;
    float ea[EDIMK];
#pragma unroll
    for (int k4 = 0; k4 < EDIMK; k4 += 4) {
        float4 v = ld4(edge_attr + (size_t)e * EDIMK + k4);
        ea[k4] = v.x; ea[k4 + 1] = v.y; ea[k4 + 2] = v.z; ea[k4 + 3] = v.w;
    }
#pragma unroll
    for (int h = 0; h < HH; ++h) {
        float s = 0.f;
#pragma unroll
        for (int k = 0; k < EDIMK; ++k) s += ea[k] * sw[k * HH + h];
        a_edge[(size_t)e * HH + h] = s;
    }
    atomicAdd(&deg[ei[EE + e]], 1);
}

// ---- 3-phase scan: deg -> rowptr (exclusive) ----
__global__ __launch_bounds__(256) void k_scan1(const int* __restrict__ deg,
                                               int* __restrict__ rowptr,
                                               int* __restrict__ part) {
    __shared__ int wsum[4];
    int tid = threadIdx.x, wid = tid >> 6, lane = tid & 63;
    int g = blockIdx.x * 256 + tid;
    int v = (g < NN) ? deg[g] : 0;
    int s = v;
#pragma unroll
    for (int off = 1; off < 64; off <<= 1) {
        int t = __shfl_up(s, off, 64);
        if (lane >= off) s += t;
    }
    if (lane == 63) wsum[wid] = s;
    __syncthreads();
    int woff = 0;
    for (int i = 0; i < wid; ++i) woff += wsum[i];
    s += woff;
    if (g < NN) rowptr[g + 1] = s;
    if (tid == 255) part[blockIdx.x] = s;
}
__global__ __launch_bounds__(256) void k_scan2(int* __restrict__ part) {
    __shared__ int wsum[4];
    int tid = threadIdx.x, wid = tid >> 6, lane = tid & 63;
    int v = (tid < NPARTS) ? part[tid] : 0;
    int s = v;
#pragma unroll
    for (int off = 1; off < 64; off <<= 1) {
        int t = __shfl_up(s, off, 64);
        if (lane >= off) s += t;
    }
    if (lane == 63) wsum[wid] = s;
    __syncthreads();
    int woff = 0;
    for (int i = 0; i < wid; ++i) woff += wsum[i];
    s += woff;
    if (tid < NPARTS) part[tid] = s - v;   // exclusive
}
__global__ __launch_bounds__(256) void k_scan3(int* __restrict__ rowptr,
                                               const int* __restrict__ part) {
    int g = blockIdx.x * 256 + threadIdx.x;
    if (g == 0) rowptr[0] = 0;
    if (g < NN) rowptr[g + 1] += part[blockIdx.x];
}

__global__ void k_scatter(const int* __restrict__ ei, const int* __restrict__ rowptr,
                          int* __restrict__ cursor, int* __restrict__ s_src,
                          int* __restrict__ s_eid) {
    int e = blockIdx.x * blockDim.x + threadIdx.x;
    if (e >= EE) return;
    int dst = ei[EE + e];
    int p = rowptr[dst] + atomicAdd(&cursor[dst], 1);
    s_src[p] = ei[e];
    s_eid[p] = e;
}

// ---- permute a_edge into CSR order ----
__global__ void k_permute(const int* __restrict__ s_eid, const float* __restrict__ a_edge,
                          float* __restrict__ ae_csr) {
    size_t t = (size_t)blockIdx.x * blockDim.x + threadIdx.x;
    if (t >= (size_t)EE * HH) return;
    ae_csr[t] = a_edge[(size_t)s_eid[t >> 3] * HH + (t & 7)];
}

// ---- self-loop a_edge = mean of incoming ----
__global__ void k_selfmean(const int* __restrict__ rowptr, const float* __restrict__ ae_csr,
                           float* __restrict__ a_self) {
    int t = blockIdx.x * blockDim.x + threadIdx.x;
    if (t >= NN * HH) return;
    int n = t >> 3, h = t & 7;
    int k0 = rowptr[n], k1 = rowptr[n + 1];
    float s = 0.f;
    for (int k = k0; k < k1; ++k) s += ae_csr[(size_t)k * HH + h];
    int d = k1 - k0; if (d < 1) d = 1;
    a_self[t] = s / (float)d;
}

// ---- weight transpose + bf16 convert: dst[b][n][k] = src[b][k][n] ----
__global__ __launch_bounds__(1024) void k_trans(const float* __restrict__ src,
                                                ushort* __restrict__ dst, int K, int N) {
    __shared__ float s[32][33];
    const float* S = src + (size_t)blockIdx.z * K * N;
    ushort* D = dst + (size_t)blockIdx.z * K * N;
    int n0 = blockIdx.x * 32, k0 = blockIdx.y * 32;
    s[threadIdx.y][threadIdx.x] = S[(size_t)(k0 + threadIdx.y) * N + n0 + threadIdx.x];
    __syncthreads();
    D[(size_t)(n0 + threadIdx.y) * K + k0 + threadIdx.x] = f2b(s[threadIdx.x][threadIdx.y]);
}

// ---- m = x ; m_b = bf16(x) ----
__global__ void k_cvt(const float* __restrict__ x, float* __restrict__ m,
                      ushort* __restrict__ mb) {
    int t = blockIdx.x * blockDim.x + threadIdx.x;
    if (t >= NN * DD) return;
    float v = x[t];
    m[t] = v;
    mb[t] = f2b(v);
}

// ---- bf16 MFMA GEMM: C[M,Nc] = A[M,K] @ Bt[Nc,K]^T, 128x128 tile, BK=64 ----
// mode 1: bf16 out (no bias); 2: bf16 + bias + relu
__global__ __launch_bounds__(256) void k_gemm_bf16(const ushort* __restrict__ A,
                                                   const ushort* __restrict__ Bt,
                                                   const float* __restrict__ bias,
                                                   void* __restrict__ Cout,
                                                   int Nc, int K, int mode) {
    __shared__ ushort As[128 * 64];
    __shared__ ushort Bs[128 * 64];
    int tid = threadIdx.x;
    int w = tid >> 6, lane = tid & 63;
    int tileM = blockIdx.y * 128, tileN = blockIdx.x * 128;
    const ushort* gA[4]; const ushort* gB[4];
    ushort* lA[4]; ushort* lB[4];
#pragma unroll
    for (int p = 0; p < 4; ++p) {
        int c = (p * 4 + w) * 64 + lane;
        int row = c >> 3, slot = c & 7;
        int gs = slot ^ (row & 7);
        gA[p] = A + (size_t)(tileM + row) * K + gs * 8;
        gB[p] = Bt + (size_t)(tileN + row) * K + gs * 8;
        lA[p] = As + (size_t)c * 8;
        lB[p] = Bs + (size_t)c * 8;
    }
    int wr = w >> 1, wc = w & 1;
    int fr = lane & 15, q = lane >> 4;
    floatx4 acc[4][4] = {};
    for (int k0 = 0; k0 < K; k0 += 64) {
        __syncthreads();
#pragma unroll
        for (int p = 0; p < 4; ++p) gload_lds16(gA[p] + k0, lA[p]);
#pragma unroll
        for (int p = 0; p < 4; ++p) gload_lds16(gB[p] + k0, lB[p]);
        __syncthreads();
#pragma unroll
        for (int kc = 0; kc < 2; ++kc) {
            int ps = ((kc * 4 + q) ^ (fr & 7)) * 8;
            short8 af[4], bf[4];
#pragma unroll
            for (int i = 0; i < 4; ++i)
                af[i] = *(const short8*)(As + (wr * 64 + i * 16 + fr) * 64 + ps);
#pragma unroll
            for (int j = 0; j < 4; ++j)
                bf[j] = *(const short8*)(Bs + (wc * 64 + j * 16 + fr) * 64 + ps);
#pragma unroll
            for (int i = 0; i < 4; ++i)
#pragma unroll
                for (int j = 0; j < 4; ++j)
                    acc[i][j] = __builtin_amdgcn_mfma_f32_16x16x32_bf16(af[i], bf[j], acc[i][j], 0, 0, 0);
        }
    }
    int rbase = tileM + wr * 64 + q * 4;
    int cbase = tileN + wc * 64 + fr;
#pragma unroll
    for (int j = 0; j < 4; ++j) {
        int col = cbase + j * 16;
        float bb = (mode != 1) ? bias[col] : 0.f;
#pragma unroll
        for (int i = 0; i < 4; ++i) {
            int row = rbase + i * 16;
#pragma unroll
            for (int r = 0; r < 4; ++r) {
                float v = acc[i][j][r] + bb;
                if (mode == 2 && v < 0.f) v = 0.f;
                ((ushort*)Cout)[(size_t)(row + r) * Nc + col] = f2b(v);
            }
        }
    }
}

// ---- FFN2 + residual + LN2 fused: tile 64 rows x 256 cols (full width), K=1024 ----
// m (fp32, chunk-offset) is residual in/out; mb bf16 out. rowsValid = NN - r0.
__global__ __launch_bounds__(256) void k_gemm2_ln(const ushort* __restrict__ A,
                                                  const ushort* __restrict__ Bt,
                                                  const float* __restrict__ bias,
                                                  const float* __restrict__ gma,
                                                  const float* __restrict__ bta,
                                                  float* __restrict__ m,
                                                  ushort* __restrict__ mb,
                                                  int rowsValid) {
    __shared__ ushort As[64 * 64];
    __shared__ ushort Bs[256 * 64];
    __shared__ float redS[64][4];
    __shared__ float redQ[64][4];
    const int K = HID;
    int tid = threadIdx.x;
    int w = tid >> 6, lane = tid & 63;
    int tileM = blockIdx.x * 64;
    int rA = tid >> 3, sl = tid & 7;
    int gs = sl ^ (rA & 7);
    const ushort* gA = A + (size_t)(tileM + rA) * K + gs * 8;
    const ushort* gB = Bt + (size_t)rA * K + gs * 8;
    ushort* lA = As + (size_t)tid * 8;
    ushort* lB = Bs + (size_t)tid * 8;
    int fr = lane & 15, q = lane >> 4;
    floatx4 acc[4][4] = {};
    for (int k0 = 0; k0 < K; k0 += 64) {
        __syncthreads();
        gload_lds16(gA + k0, lA);
        gload_lds16(gA + (size_t)32 * K + k0, lA + 256 * 8);
#pragma unroll
        for (int p = 0; p < 8; ++p)
            gload_lds16(gB + (size_t)p * 32 * K + k0, lB + (size_t)p * 256 * 8);
        __syncthreads();
#pragma unroll
        for (int kc = 0; kc < 2; ++kc) {
            int ps = ((kc * 4 + q) ^ (fr & 7)) * 8;
            short8 af[4], bf[4];
#pragma unroll
            for (int i = 0; i < 4; ++i)
                af[i] = *(const short8*)(As + (i * 16 + fr) * 64 + ps);
#pragma unroll
            for (int j = 0; j < 4; ++j)
                bf[j] = *(const short8*)(Bs + (w * 64 + j * 16 + fr) * 64 + ps);
#pragma unroll
            for (int i = 0; i < 4; ++i)
#pragma unroll
                for (int j = 0; j < 4; ++j)
                    acc[i][j] = __builtin_amdgcn_mfma_f32_16x16x32_bf16(af[i], bf[j], acc[i][j], 0, 0, 0);
        }
    }
    // epilogue: bias + residual, per-row LN over 256 cols
    int colb = w * 64 + fr;
    float bw[4], gw[4], btw[4];
#pragma unroll
    for (int j = 0; j < 4; ++j) {
        bw[j] = bias[colb + j * 16];
        gw[j] = gma[colb + j * 16];
        btw[j] = bta[colb + j * 16];
    }
#pragma unroll
    for (int i = 0; i < 4; ++i) {
#pragma unroll
        for (int rr = 0; rr < 4; ++rr) {
            int lrow = i * 16 + q * 4 + rr;
            int grow = tileM + lrow;
            bool valid = grow < rowsValid;
            float s = 0.f, s2 = 0.f;
#pragma unroll
            for (int j = 0; j < 4; ++j) {
                float rres = valid ? m[(size_t)grow * DD + colb + j * 16] : 0.f;
                float gv = acc[i][j][rr] + bw[j] + rres;
                acc[i][j][rr] = gv;
                s += gv; s2 += gv * gv;
            }
#pragma unroll
            for (int msk = 1; msk < 16; msk <<= 1) {
                s += __shfl_xor(s, msk, 16);
                s2 += __shfl_xor(s2, msk, 16);
            }
            if (fr == 0) { redS[lrow][w] = s; redQ[lrow][w] = s2; }
        }
    }
    __syncthreads();
#pragma unroll
    for (int i = 0; i < 4; ++i) {
#pragma unroll
        for (int rr = 0; rr < 4; ++rr) {
            int lrow = i * 16 + q * 4 + rr;
            int grow = tileM + lrow;
            if (grow >= rowsValid) continue;
            float su = redS[lrow][0] + redS[lrow][1] + redS[lrow][2] + redS[lrow][3];
            float sq = redQ[lrow][0] + redQ[lrow][1] + redQ[lrow][2] + redQ[lrow][3];
            float mu = su * (1.0f / DD);
            float var = sq * (1.0f / DD) - mu * mu;
            float rs = rsqrtf(var + LNEPS);
#pragma unroll
            for (int j = 0; j < 4; ++j) {
                float v = (acc[i][j][rr] - mu) * rs * gw[j] + btw[j];
                size_t idx = (size_t)grow * DD + colb + j * 16;
                m[idx] = v;
                mb[idx] = f2b(v);
            }
        }
    }
}

// ---- a_src/a_dst from bf16 x_proj ----
__global__ void k_srcdst(const ushort* __restrict__ xb, const float* __restrict__ att_src,
                         const float* __restrict__ att_dst, float* __restrict__ a_src,
                         float* __restrict__ a_dst) {
    __shared__ float ss[DD], sd[DD];
    int tid = threadIdx.x;
    if (tid < DD) { ss[tid] = att_src[tid]; sd[tid] = att_dst[tid]; }
    __syncthreads();
    int t = blockIdx.x * blockDim.x + tid;
    if (t >= NN * HH) return;
    int n = t >> 3, h = t & 7;
    const ushort* xp = xb + (size_t)n * DD + h * CC;
    float s1 = 0.f, s2 = 0.f;
#pragma unroll
    for (int c = 0; c < CC; c += 4) {
        ushort4 u = *(const ushort4*)(xp + c);
        float vx = b2f(u.x), vy = b2f(u.y), vz = b2f(u.z), vw = b2f(u.w);
        int b = h * CC + c;
        s1 += vx * ss[b] + vy * ss[b + 1] + vz * ss[b + 2] + vw * ss[b + 3];
        s2 += vx * sd[b] + vy * sd[b + 1] + vz * sd[b + 2] + vw * sd[b + 3];
    }
    a_src[t] = s1;
    a_dst[t] = s2;
}

// ---- fused softmax-aggregate + bias + residual + LN1 : 2 nodes/wave, 4-edge unroll ----
__global__ __launch_bounds__(256) void k_agg(const ushort* __restrict__ xb,
                                             const float* __restrict__ a_src,
                                             const float* __restrict__ a_dst,
                                             const float* __restrict__ a_self,
                                             const int* __restrict__ rowptr,
                                             const int* __restrict__ s_src,
                                             const float* __restrict__ ae_csr,
                                             const float* __restrict__ bias,
                                             const float* __restrict__ gma,
                                             const float* __restrict__ bta,
                                             float* __restrict__ m,
                                             ushort* __restrict__ mb) {
    int wid = (blockIdx.x * blockDim.x + threadIdx.x) >> 6;
    int lane = threadIdx.x & 63;
    int n = wid * 2 + (lane >> 5);
    if (n >= NN) return;
    int hl = lane & 31, h = hl >> 2, c8 = hl * 8;
    float adn = a_dst[n * HH + h];
    float al0 = a_src[n * HH + h] + adn + a_self[n * HH + h];
    al0 = al0 > 0.f ? al0 : NEG * al0;
    float w0 = __expf(al0);
    ushort8 xs = *(const ushort8*)(xb + (size_t)n * DD + c8);
    float acc[8];
#pragma unroll
    for (int i = 0; i < 8; ++i) acc[i] = w0 * b2f(xs[i]);
    float den = w0;
    int k = rowptr[n], k1 = rowptr[n + 1];
    for (; k + 3 < k1; k += 4) {
        int s0 = s_src[k], s1 = s_src[k + 1], s2 = s_src[k + 2], s3 = s_src[k + 3];
        float e0 = ae_csr[(size_t)k * HH + h];
        float e1 = ae_csr[(size_t)(k + 1) * HH + h];
        float e2 = ae_csr[(size_t)(k + 2) * HH + h];
        float e3 = ae_csr[(size_t)(k + 3) * HH + h];
        float t0 = a_src[(size_t)s0 * HH + h] + adn + e0;
        float t1 = a_src[(size_t)s1 * HH + h] + adn + e1;
        float t2 = a_src[(size_t)s2 * HH + h] + adn + e2;
        float t3 = a_src[(size_t)s3 * HH + h] + adn + e3;
        ushort8 v0 = *(const ushort8*)(xb + (size_t)s0 * DD + c8);
        ushort8 v1 = *(const ushort8*)(xb + (size_t)s1 * DD + c8);
        ushort8 v2 = *(const ushort8*)(xb + (size_t)s2 * DD + c8);
        ushort8 v3 = *(const ushort8*)(xb + (size_t)s3 * DD + c8);
        t0 = t0 > 0.f ? t0 : NEG * t0;
        t1 = t1 > 0.f ? t1 : NEG * t1;
        t2 = t2 > 0.f ? t2 : NEG * t2;
        t3 = t3 > 0.f ? t3 : NEG * t3;
        float wv0 = __expf(t0), wv1 = __expf(t1), wv2 = __expf(t2), wv3 = __expf(t3);
        den += (wv0 + wv1) + (wv2 + wv3);
#pragma unroll
        for (int i = 0; i < 8; ++i)
            acc[i] += (wv0 * b2f(v0[i]) + wv1 * b2f(v1[i])) + (wv2 * b2f(v2[i]) + wv3 * b2f(v3[i]));
    }
    for (; k < k1; ++k) {
        int s0 = s_src[k];
        float t0 = a_src[(size_t)s0 * HH + h] + adn + ae_csr[(size_t)k * HH + h];
        t0 = t0 > 0.f ? t0 : NEG * t0;
        float wv0 = __expf(t0);
        ushort8 v0 = *(const ushort8*)(xb + (size_t)s0 * DD + c8);
        den += wv0;
#pragma unroll
        for (int i = 0; i < 8; ++i) acc[i] += wv0 * b2f(v0[i]);
    }
    float inv = 1.f / den;
    size_t base = (size_t)n * DD + c8;
    float4 mr0 = ld4(m + base), mr1 = ld4(m + base + 4);
    float4 b0 = ld4(bias + c8), b1 = ld4(bias + c8 + 4);
    float g[8];
    g[0] = acc[0] * inv + b0.x + mr0.x; g[1] = acc[1] * inv + b0.y + mr0.y;
    g[2] = acc[2] * inv + b0.z + mr0.z; g[3] = acc[3] * inv + b0.w + mr0.w;
    g[4] = acc[4] * inv + b1.x + mr1.x; g[5] = acc[5] * inv + b1.y + mr1.y;
    g[6] = acc[6] * inv + b1.z + mr1.z; g[7] = acc[7] * inv + b1.w + mr1.w;
    float s = 0.f;
#pragma unroll
    for (int i = 0; i < 8; ++i) s += g[i];
#pragma unroll
    for (int off = 16; off; off >>= 1) s += __shfl_xor(s, off, 64);
    float mu = s * (1.0f / DD);
    float qv = 0.f;
#pragma unroll
    for (int i = 0; i < 8; ++i) { g[i] -= mu; qv += g[i] * g[i]; }
#pragma unroll
    for (int off = 16; off; off >>= 1) qv += __shfl_xor(qv, off, 64);
    float rs = rsqrtf(qv * (1.0f / DD) + LNEPS);
    float4 g0 = ld4(gma + c8), g1 = ld4(gma + c8 + 4);
    float4 bb0 = ld4(bta + c8), bb1 = ld4(bta + c8 + 4);
    float o[8];
    o[0] = g[0] * rs * g0.x + bb0.x; o[1] = g[1] * rs * g0.y + bb0.y;
    o[2] = g[2] * rs * g0.z + bb0.z; o[3] = g[3] * rs * g0.w + bb0.w;
    o[4] = g[4] * rs * g1.x + bb1.x; o[5] = g[5] * rs * g1.y + bb1.y;
    o[6] = g[6] * rs * g1.z + bb1.z; o[7] = g[7] * rs * g1.w + bb1.w;
    st4(m + base, make_float4(o[0], o[1], o[2], o[3]));
    st4(m + base + 4, make_float4(o[4], o[5], o[6], o[7]));
    ushort8 ob;
#pragma unroll
    for (int i = 0; i < 8; ++i) ob[i] = f2b(o[i]);
    *reinterpret_cast<ushort8*>(mb + base) = ob;
}

extern "C" void kernel_launch(void* const* d_in, const int* in_sizes, int n_in,
                              void* d_out, int out_size, void* d_ws, size_t ws_size,
                              hipStream_t stream) {
    const float* x        = (const float*)d_in[0];
    const int*   ei       = (const int*)d_in[1];
    const float* edge_attr= (const float*)d_in[2];
    const float* W        = (const float*)d_in[3];
    const float* att_src  = (const float*)d_in[4];
    const float* att_dst  = (const float*)d_in[5];
    const float* att_edge = (const float*)d_in[6];
    const float* W_edge   = (const float*)d_in[7];
    const float* bias     = (const float*)d_in[8];
    const float* ffn_w1   = (const float*)d_in[9];
    const float* ffn_b1   = (const float*)d_in[10];
    const float* ffn_w2   = (const float*)d_in[11];
    const float* ffn_b2   = (const float*)d_in[12];
    const float* ln1_g    = (const float*)d_in[13];
    const float* ln1_b    = (const float*)d_in[14];
    const float* ln2_g    = (const float*)d_in[15];
    const float* ln2_b    = (const float*)d_in[16];
    float* m = (float*)d_out;

    char* wp = (char*)d_ws;
    auto alloc = [&](size_t bytes) -> char* {
        char* p = wp;
        wp += (bytes + 255) & ~(size_t)255;
        return p;
    };
    float*  a_edge = (float*)alloc((size_t)EE * HH * 4);
    float*  ae_csr = (float*)alloc((size_t)EE * HH * 4);
    float*  a_self = (float*)alloc((size_t)NN * HH * 4);
    float*  a_src  = (float*)alloc((size_t)NN * HH * 4);
    float*  a_dst  = (float*)alloc((size_t)NN * HH * 4);
    int*    deg    = (int*)alloc((size_t)NN * 4);
    int*    rowptr = (int*)alloc((size_t)(NN + 1) * 4);
    int*    cursor = (int*)alloc((size_t)NN * 4);
    int*    part   = (int*)alloc((size_t)NPARTS * 4);
    int*    s_src  = (int*)alloc((size_t)EE * 4);
    int*    s_eid  = (int*)alloc((size_t)EE * 4);
    float*  w_eh   = (float*)alloc((size_t)EDIMK * HH * 4);
    ushort* Wt     = (ushort*)alloc((size_t)DD * DD * 2);
    ushort* w1t    = (ushort*)alloc((size_t)LL * DD * HID * 2);
    ushort* w2t    = (ushort*)alloc((size_t)LL * HID * DD * 2);
    ushort* xprojb = (ushort*)alloc((size_t)MP * DD * 2);
    ushort* m_b    = (ushort*)alloc((size_t)MP * DD * 2);
    size_t used = (size_t)(wp - (char*)d_ws);
    size_t avail = ws_size > used ? ws_size - used : 0;
    size_t maxrows = avail / ((size_t)HID * 2);
    int chunkP = (int)((maxrows / 128) * 128);
    if (chunkP < 128) chunkP = 128;
    if (chunkP > MP) chunkP = MP;
    ushort* h1b = (ushort*)wp;

    hipMemsetAsync(deg, 0, (size_t)NN * 4, stream);
    hipMemsetAsync(cursor, 0, (size_t)NN * 4, stream);

    // layer-invariant precompute
    k_weh<<<1, 128, 0, stream>>>(W_edge, att_edge, w_eh);
    k_edge_pre<<<(EE + 255) / 256, 256, 0, stream>>>(edge_attr, ei, w_eh, a_edge, deg);
    k_scan1<<<NPARTS, 256, 0, stream>>>(deg, rowptr, part);
    k_scan2<<<1, 256, 0, stream>>>(part);
    k_scan3<<<NPARTS, 256, 0, stream>>>(rowptr, part);
    k_scatter<<<(EE + 255) / 256, 256, 0, stream>>>(ei, rowptr, cursor, s_src, s_eid);
    k_permute<<<(EE * HH + 255) / 256, 256, 0, stream>>>(s_eid, a_edge, ae_csr);
    k_selfmean<<<(NN * HH + 255) / 256, 256, 0, stream>>>(rowptr, ae_csr, a_self);
    // weights -> bf16 transposed
    k_trans<<<dim3(DD / 32, DD / 32, 1), dim3(32, 32), 0, stream>>>(W, Wt, DD, DD);
    k_trans<<<dim3(HID / 32, DD / 32, LL), dim3(32, 32), 0, stream>>>(ffn_w1, w1t, DD, HID);
    k_trans<<<dim3(DD / 32, HID / 32, LL), dim3(32, 32), 0, stream>>>(ffn_w2, w2t, HID, DD);
    // m = x, m_b = bf16(x)
    k_cvt<<<(NN * DD + 255) / 256, 256, 0, stream>>>(x, m, m_b);

    for (int i = 0; i < LL; ++i) {
        k_gemm_bf16<<<dim3(DD / 128, MP / 128), 256, 0, stream>>>(m_b, Wt, nullptr, xprojb, DD, DD, 1);
        k_srcdst<<<(NN * HH + 255) / 256, 256, 0, stream>>>(xprojb, att_src, att_dst, a_src, a_dst);
        k_agg<<<((NN + 1) / 2 * 64 + 255) / 256, 256, 0, stream>>>(xprojb, a_src, a_dst, a_self,
                                                                   rowptr, s_src, ae_csr, bias,
                                                                   ln1_g + i * DD, ln1_b + i * DD, m, m_b);
        for (int r0 = 0; r0 < MP; r0 += chunkP) {
            int rows = (MP - r0) < chunkP ? (MP - r0) : chunkP;
            k_gemm_bf16<<<dim3(HID / 128, rows / 128), 256, 0, stream>>>(
                m_b + (size_t)r0 * DD, w1t + (size_t)i * DD * HID,
                ffn_b1 + (size_t)i * HID, h1b, HID, DD, 2);
            k_gemm2_ln<<<rows / 64, 256, 0, stream>>>(
                h1b, w2t + (size_t)i * HID * DD, ffn_b2 + (size_t)i * DD,
                ln2_g + i * DD, ln2_b + i * DD,
                m + (size_t)r0 * DD, m_b + (size_t)r0 * DD, NN - r0);
        }
    }
}